// Round 13
// baseline (399.620 us; speedup 1.0000x reference)
//
#include <hip/hip_runtime.h>
#include <hip/hip_bf16.h>
#include <math.h>

typedef unsigned short ushort_t;
typedef __attribute__((ext_vector_type(8))) short short8;
typedef __attribute__((ext_vector_type(4))) short s4v;
typedef __attribute__((ext_vector_type(4))) float float4v;
typedef __attribute__((ext_vector_type(16))) float f32x16;

#define HID 1024
#define NH 8
#define DH 128
#define CHUNK 12
#define PAST 12
#define CTX 24
#define NPOS 25
#define QKVW 3072

__device__ __forceinline__ float bf2f(ushort_t b){
  union{unsigned int u; float f;} x; x.u = ((unsigned int)b)<<16; return x.f;
}
__device__ __forceinline__ ushort_t f2bf(float f){
  union{float f; unsigned int u;} x; x.f = f;
  unsigned int u = x.u;
  unsigned int r = u + 0x7fffu + ((u>>16)&1u);
  return (ushort_t)(r>>16);
}

__device__ __forceinline__ void gload16(const ushort_t* g, ushort_t* l){
  __builtin_amdgcn_global_load_lds(
      (const __attribute__((address_space(1))) unsigned int*)g,
      (__attribute__((address_space(3))) unsigned int*)l,
      16, 0, 0);
}

// one launch: hs -> hsb, Wq|Wk|Wv -> Wcat, Wpost -> Wpb (f32 -> bf16)
__global__ __launch_bounds__(256) void cvt_all(
    const float* __restrict__ hs, const float* __restrict__ Wq,
    const float* __restrict__ Wk, const float* __restrict__ Wv,
    const float* __restrict__ Wp, ushort_t* __restrict__ hsb,
    ushort_t* __restrict__ Wcat, ushort_t* __restrict__ Wpb, int nhs4)
{
  const int W4 = 262144;               // (1024*1024)/4
  const int total = nhs4 + 4*W4;
  for (int i = blockIdx.x*256 + threadIdx.x; i < total; i += gridDim.x*256){
    const float4v* src; s4v* dst; int off;
    if (i < nhs4){ src = (const float4v*)hs; dst = (s4v*)hsb; off = i; }
    else {
      int j = i - nhs4; int seg = j >> 18; off = j & (W4-1);
      src = (const float4v*)(seg==0?Wq:seg==1?Wk:seg==2?Wv:Wp);
      dst = (seg<3) ? ((s4v*)Wcat) + (size_t)seg*W4 : (s4v*)Wpb;
    }
    float4v v = src[off];
    s4v o;
#pragma unroll
    for (int j2=0;j2<4;j2++) o[j2] = (short)f2bf(v[j2]);
    dst[off] = o;
  }
}

// ===== 128x128 BK=32 3-slot-ring counted-vmcnt GEMM, 32x32x16 MFMA core =====
// LDS placement: row r, 16B-slot s stored at phys r*32 + (s^((r>>1)&3))*8.
// For fixed s, rows 0..7 hit bank-groups {s,4+s^..} = all 8 (low {s^0..s^3}=
// {0..3}, high +4) -> whole-wave b128 reads are group-uniform (throughput
// floor). Staging inverse (rule 21): lane l sources global k-slot
// (l&3)^((l>>3)&3) of row l>>2; gload_lds dest linear; reads apply same XOR.
// Wave out 64x64 = 2x2 mfma_f32_32x32x16_bf16; per BK=32 tile: 8 ds_read +
// 8 MFMA (was 12+16). C/D: col=lane&31, row=(reg&3)+8*(reg>>2)+4*(lane>>5).
template<int MODE, int OUTF>
__global__ __launch_bounds__(256) void gemm3(
    const ushort_t* __restrict__ A, const ushort_t* __restrict__ W,
    void* __restrict__ Cv, int M, int N, int K,
    const float* __restrict__ pds, float qsc, float ksc)
{
  const int nwg  = gridDim.x;
  const int orig = blockIdx.x;
  const int qch  = nwg >> 3, rch = nwg & 7;
  const int xcd  = orig & 7, idx = orig >> 3;
  const int bid  = (xcd < rch ? xcd*(qch+1) : rch*(qch+1) + (xcd-rch)*qch) + idx;

  const int NT = N >> 7;
  const int m0 = (bid / NT) * 128;
  const int n0 = (bid % NT) * 128;

  const int tid  = threadIdx.x;
  const int w    = tid >> 6, lane = tid & 63;
  const int wm   = w >> 1, wn = w & 1;
  const int rl   = lane & 31;          // fragment row
  const int sh   = lane >> 5;          // k-half 0/1
  const int xr   = (rl >> 1) & 3;      // placement XOR (lane-constant)

  __shared__ ushort_t slab[6*128*32];          // 48KB: 3 x (A,B)
  ushort_t* a0 = slab;                 ushort_t* b0 = slab + 128*32;
  ushort_t* a1 = slab + 2*128*32;      ushort_t* b1 = slab + 3*128*32;
  ushort_t* a2 = slab + 4*128*32;      ushort_t* b2 = slab + 5*128*32;

  f32x16 acc[2][2];
#pragma unroll
  for (int i=0;i<2;i++)
#pragma unroll
    for (int j=0;j<2;j++) acc[i][j] = (f32x16)0.0f;

  // staging source permutation: lane l -> row l>>2, global slot (l&3)^((l>>3)&3)
  const int sr = lane >> 2;
  const int sc = ((lane & 3) ^ ((lane >> 3) & 3)) * 8;

  // read-side lane-constant offsets: phys slot for (global slot s) = s ^ xr
  const int ps0 = ((0*2 + sh) ^ xr) * 8;   // kh=0
  const int ps1 = ((1*2 + sh) ^ xr) * 8;   // kh=16
  const int aR0 = (wm*64      + rl)*32;    // mi=0
  const int aR1 = (wm*64 + 32 + rl)*32;    // mi=1
  const int bR0 = (wn*64      + rl)*32;
  const int bR1 = (wn*64 + 32 + rl)*32;

  const ushort_t* Ab0 = A + (size_t)(m0 + w*16      + sr)*K + sc;
  const ushort_t* Ab1 = A + (size_t)(m0 + 64 + w*16 + sr)*K + sc;
  const ushort_t* Bb0 = W + (size_t)(n0 + w*16      + sr)*K + sc;
  const ushort_t* Bb1 = W + (size_t)(n0 + 64 + w*16 + sr)*K + sc;

#define STAGE(Abuf, Bbuf, kt) do {                    \
    gload16(Ab0 + (kt), &(Abuf)[(w*16)*32]);          \
    gload16(Ab1 + (kt), &(Abuf)[(64 + w*16)*32]);     \
    gload16(Bb0 + (kt), &(Bbuf)[(w*16)*32]);          \
    gload16(Bb1 + (kt), &(Bbuf)[(64 + w*16)*32]);     \
  } while(0)

#define COMPUTE(Abuf, Bbuf) do {                                             \
    short8 fa0 = *(const short8*)&(Abuf)[aR0 + ps0];                         \
    short8 fa1 = *(const short8*)&(Abuf)[aR1 + ps0];                         \
    short8 fb0 = *(const short8*)&(Bbuf)[bR0 + ps0];                         \
    short8 fb1 = *(const short8*)&(Bbuf)[bR1 + ps0];                         \
    __builtin_amdgcn_s_setprio(1);                                           \
    acc[0][0] = __builtin_amdgcn_mfma_f32_32x32x16_bf16(fa0, fb0, acc[0][0], 0,0,0); \
    acc[0][1] = __builtin_amdgcn_mfma_f32_32x32x16_bf16(fa0, fb1, acc[0][1], 0,0,0); \
    acc[1][0] = __builtin_amdgcn_mfma_f32_32x32x16_bf16(fa1, fb0, acc[1][0], 0,0,0); \
    acc[1][1] = __builtin_amdgcn_mfma_f32_32x32x16_bf16(fa1, fb1, acc[1][1], 0,0,0); \
    __builtin_amdgcn_s_setprio(0);                                           \
    short8 ga0 = *(const short8*)&(Abuf)[aR0 + ps1];                         \
    short8 ga1 = *(const short8*)&(Abuf)[aR1 + ps1];                         \
    short8 gb0 = *(const short8*)&(Bbuf)[bR0 + ps1];                         \
    short8 gb1 = *(const short8*)&(Bbuf)[bR1 + ps1];                         \
    __builtin_amdgcn_s_setprio(1);                                           \
    acc[0][0] = __builtin_amdgcn_mfma_f32_32x32x16_bf16(ga0, gb0, acc[0][0], 0,0,0); \
    acc[0][1] = __builtin_amdgcn_mfma_f32_32x32x16_bf16(ga0, gb1, acc[0][1], 0,0,0); \
    acc[1][0] = __builtin_amdgcn_mfma_f32_32x32x16_bf16(ga1, gb0, acc[1][0], 0,0,0); \
    acc[1][1] = __builtin_amdgcn_mfma_f32_32x32x16_bf16(ga1, gb1, acc[1][1], 0,0,0); \
    __builtin_amdgcn_s_setprio(0);                                           \
  } while(0)

  const int nt = K >> 5;
  STAGE(a0, b0, 0);
  STAGE(a1, b1, 32);

  for (int t = 0; t < nt; ++t){
    if (t == nt-1) asm volatile("s_waitcnt vmcnt(0)" ::: "memory");
    else           asm volatile("s_waitcnt vmcnt(4)" ::: "memory");
    asm volatile("s_barrier" ::: "memory");
    if (t+2 < nt) STAGE(a2, b2, (t+2)*32);
    COMPUTE(a0, b0);
    ushort_t* ta = a0; a0 = a1; a1 = a2; a2 = ta;
    ushort_t* tb = b0; b0 = b1; b1 = b2; b2 = tb;
  }
#undef STAGE
#undef COMPUTE

  __syncthreads();

  if (OUTF == 0){
#pragma unroll
    for (int nj=0; nj<2; nj++){
      const int col = wn*64 + nj*32 + rl;
      float scale = 1.0f;
      if (MODE==1){
        const int gcol = n0 + col;
        if (gcol < 1024){ float p = pds[gcol & (DH-1)]; scale = qsc * log1pf(expf(p)); }
        else if (gcol < 2048) scale = ksc;
      }
#pragma unroll
      for (int mi=0; mi<2; mi++){
#pragma unroll
        for (int reg=0; reg<16; reg++){
          const int row = wm*64 + mi*32 + (reg&3) + 8*(reg>>2) + 4*sh;
          slab[row*128 + col] = f2bf(acc[mi][nj][reg] * scale);
        }
      }
    }
    __syncthreads();
    ushort_t* Crow = (ushort_t*)Cv + (size_t)m0*N + n0;
    const int rr = tid >> 4, sl = (tid & 15)*8;
#pragma unroll
    for (int it=0; it<8; ++it){
      const int row = it*16 + rr;
      *(short8*)&Crow[(size_t)row*N + sl] = *(const short8*)&slab[row*128 + sl];
    }
  } else {
    float* smf = (float*)slab;
    float* Crow = (float*)Cv + (size_t)m0*N + n0;
#pragma unroll
    for (int h2=0; h2<2; ++h2){
      __syncthreads();
      if (wm == h2){
#pragma unroll
        for (int nj=0; nj<2; nj++){
          const int col = wn*64 + nj*32 + rl;
#pragma unroll
          for (int mi=0; mi<2; mi++){
#pragma unroll
            for (int reg=0; reg<16; reg++){
              const int lrow = mi*32 + (reg&3) + 8*(reg>>2) + 4*sh;
              smf[lrow*128 + col] = acc[mi][nj][reg];
            }
          }
        }
      }
      __syncthreads();
      const int rr = tid >> 5, half = ((tid >> 4) & 1)*64, sl = (tid & 15)*4;
#pragma unroll
      for (int it=0; it<8; ++it){
        const int row = it*8 + rr;
        *(float4v*)&Crow[(size_t)(h2*64 + row)*N + half + sl] =
            *(const float4v*)&smf[row*128 + half + sl];
      }
    }
  }
}

// rel[25,1024] = pe[25,1024] @ Wrel^T, 2-way K-split + shfl combine
__global__ __launch_bounds__(256) void relk2(
    const float* __restrict__ pe, const float* __restrict__ Wrel,
    ushort_t* __restrict__ rel)
{
  int g = blockIdx.x*256 + threadIdx.x;
  int idx = g >> 1, par = g & 1;
  if (idx >= NPOS*HID) return;
  int p = idx >> 10, n = idx & 1023;
  const float* a = pe + p*HID + par*512;
  const float* w = Wrel + (size_t)n*HID + par*512;
  float s = 0.f;
  for (int k=0;k<512;k+=4){
    float4v av = *(const float4v*)(a+k);
    float4v wv = *(const float4v*)(w+k);
#pragma unroll
    for (int u=0;u<4;u++) s += av[u]*wv[u];
  }
  s += __shfl_xor(s, 1, 64);
  if (!par) rel[idx] = f2bf(s);
}

// MFMA attention, LDS lifetime-aliased: 49.6KB -> 3 blocks/CU. (passing r11)
__global__ __launch_bounds__(256) void attn_kernel(
  const ushort_t* __restrict__ qkv, const ushort_t* __restrict__ rel,
  ushort_t* __restrict__ o, int S)
{
  const int n0 = blockIdx.x * 4;
  const int b  = blockIdx.y, h = blockIdx.z;
  const int tid = threadIdx.x;
  const size_t bS = (size_t)b * S;

  __shared__ ushort_t lds[24800];
  ushort_t* ks = lds;
  ushort_t* vt = lds + 9248;
  float*    sB = (float*)(lds + 17952);
  ushort_t* rs = lds + 20448;
  float*    sA = (float*)(lds + 20448);

  const int base = n0*CHUNK - PAST;
  {
    const int r0 = tid >> 4;
    const int c0 = (tid & 15) * 8;
    for (int r = r0; r < 68; r += 16){
      int s = base + r;
      short8 kv = (short8)0, vv = (short8)0;
      if (r < 60 && s >= 0 && s < S){
        kv = *(const short8*)&qkv[(bS + s)*QKVW + 1024 + h*DH + c0];
        vv = *(const short8*)&qkv[(bS + s)*QKVW + 2048 + h*DH + c0];
      }
      *(short8*)&ks[r*136 + c0] = kv;
#pragma unroll
      for (int u=0;u<8;u++) vt[(c0+u)*68 + r] = (ushort_t)vv[u];
    }
    for (int r = r0; r < 32; r += 16){
      short8 rv = (short8)0;
      if (r < NPOS) rv = *(const short8*)&rel[r*HID + h*DH + c0];
      *(short8*)&rs[r*136 + c0] = rv;
    }
  }
  __syncthreads();

  const int w    = tid >> 6;
  const int lane = tid & 63;
  const int lr   = lane & 15;
  const int lg   = lane >> 4;

  float*    sAw = sA + w*312;
  float*    sBw = sB + w*312;
  ushort_t* Ppw = lds + w*640;

  int qrow = (n0 + w)*CHUNK + lr;
  if (qrow >= S) qrow = S - 1;
  const ushort_t* qp = qkv + (bS + qrow)*QKVW + h*DH + lg*8;
  short8 qf[4];
#pragma unroll
  for (int ks2=0; ks2<4; ks2++) qf[ks2] = *(const short8*)(qp + ks2*32);

  // BD = q @ rel^T
#pragma unroll
  for (int t0=0; t0<2; t0++){
    float4v acc = (float4v)0.0f;
#pragma unroll
    for (int ks2=0; ks2<4; ks2++){
      short8 rf = *(const short8*)&rs[(t0*16 + lr)*136 + ks2*32 + lg*8];
      acc = __builtin_amdgcn_mfma_f32_16x16x32_bf16(qf[ks2], rf, acc, 0,0,0);
    }
    const int p = t0*16 + lr;
#pragma unroll
    for (int reg=0; reg<4; reg++){
      int cr = lg*4 + reg;
      if (cr < CHUNK && p < NPOS) sBw[cr*26 + p] = acc[reg];
    }
  }
  __syncthreads();

  // AC = q @ k^T (sA aliases rs)
#pragma unroll
  for (int t0=0; t0<2; t0++){
    float4v acc = (float4v)0.0f;
#pragma unroll
    for (int ks2=0; ks2<4; ks2++){
      short8 kf = *(const short8*)&ks[(w*CHUNK + t0*16 + lr)*136 + ks2*32 + lg*8];
      acc = __builtin_amdgcn_mfma_f32_16x16x32_bf16(qf[ks2], kf, acc, 0,0,0);
    }
    const int t = t0*16 + lr;
#pragma unroll
    for (int reg=0; reg<4; reg++){
      int cr = lg*4 + reg;
      if (cr < CHUNK && t < CTX) sAw[cr*26 + t] = acc[reg];
    }
  }
  __syncthreads();

  if (lane < CHUNK) *(short8*)&Ppw[lane*40 + 24] = (short8)0;

  {
    const int c2 = lane >> 5;
    const int t  = lane & 31;
#pragma unroll
    for (int i=0;i<6;i++){
      int c = i*2 + c2;
      float x = -1e30f;
      if (t < CTX){
        int f = c*CTX + t;
        int r = f / NPOS, p = f - r*NPOS;
        x = sAw[c*26 + t] + sBw[r*26 + p];
        x = 50.0f * tanhf(x * 0.02f);
      }
      float m = x;
      for (int off=16; off>=1; off>>=1) m = fmaxf(m, __shfl_xor(m, off, 32));
      float e = (t < CTX) ? expf(x - m) : 0.0f;
      float s = e;
      for (int off=16; off>=1; off>>=1) s += __shfl_xor(s, off, 32);
      if (t < CTX) Ppw[c*40 + t] = f2bf(e / s);
    }
  }

  short8 pf = *(const short8*)&Ppw[lr*40 + lg*8];
  const int orow_base = (n0 + w)*CHUNK;
#pragma unroll
  for (int j=0; j<8; j++){
    int d  = j*16 + lr;
    int tb = w*CHUNK + lg*8;
    s4v b0 = *(const s4v*)&vt[d*68 + tb];
    s4v b1 = *(const s4v*)&vt[d*68 + tb + 4];
    short8 bf;
#pragma unroll
    for (int u=0;u<4;u++){ bf[u] = b0[u]; bf[u+4] = b1[u]; }
    float4v a = __builtin_amdgcn_mfma_f32_16x16x32_bf16(pf, bf, (float4v)0.0f, 0,0,0);
#pragma unroll
    for (int reg=0; reg<4; reg++){
      int cr = lg*4 + reg;
      if (cr < CHUNK)
        o[(bS + orow_base + cr)*HID + h*DH + j*16 + lr] = f2bf(a[reg]);
    }
  }
}

extern "C" void kernel_launch(void* const* d_in, const int* in_sizes, int n_in,
                              void* d_out, int out_size, void* d_ws, size_t ws_size,
                              hipStream_t stream)
{
  const float* hs    = (const float*)d_in[0];
  const float* pe    = (const float*)d_in[1];
  const float* Wq    = (const float*)d_in[2];
  const float* Wk    = (const float*)d_in[3];
  const float* Wv    = (const float*)d_in[4];
  const float* Wpost = (const float*)d_in[5];
  const float* Wrel  = (const float*)d_in[6];
  const float* pds   = (const float*)d_in[7];
  float* out = (float*)d_out;

  const int BS = in_sizes[0] / HID;   // 24576
  const int B  = 4;
  const int S  = BS / B;              // 6144
  const int nb = S / CHUNK;           // 512

  const size_t per = (size_t)BS * HID;
  const size_t wsz = (size_t)HID * HID;
  ushort_t* qkv  = (ushort_t*)d_ws;
  ushort_t* at   = qkv  + (size_t)BS * QKVW;
  ushort_t* rel  = at   + per;
  ushort_t* hsb  = rel  + (size_t)NPOS*HID;
  ushort_t* Wcat = hsb  + per;
  ushort_t* Wpb  = Wcat + 3*wsz;

  const float qsc = (float)(pow((double)DH, -0.5) / log(2.0));
  const float ksc = (float)(log(1.0 + exp(1.0)) / log(2.0));

  cvt_all<<<4096, 256, 0, stream>>>(hs, Wq, Wk, Wv, Wpost, hsb, Wcat, Wpb,
                                    (int)(per/4));
  relk2<<<200, 256, 0, stream>>>(pe, Wrel, rel);

  gemm3<1,0><<<(BS/128)*(QKVW/128), 256, 0, stream>>>(
      hsb, Wcat, qkv, BS, QKVW, HID, pds, qsc, ksc);
  attn_kernel<<<dim3(nb/4, B, NH), 256, 0, stream>>>(qkv, rel, at, S);
  gemm3<0,1><<<(BS/128)*(HID/128), 256, 0, stream>>>(
      at, Wpb, out, BS, HID, HID, nullptr, 1.0f, 1.0f);
}